// Round 5
// baseline (113.396 us; speedup 1.0000x reference)
//
#include <hip/hip_runtime.h>

// Lin2d: x_final = x @ (linMt)^N.  N-step linear recurrence == one matrix
// power (binary exponentiation, fp32) + one streaming pass over x.
// Traffic: 64 MiB read + 64 MiB write -> ~21.3 us floor at 6.29 TB/s
// (measured float4-copy ceiling).
//
// R2->R3: nt hints REGRESSED (forfeit LLC hits from harness restore) -> plain.
// R4->R5: 4 float4/thread (was 2) — 4 back-to-back 1 KiB wave-loads in
// flight per wave, 4 batched wave-stores; halves loop/branch overhead per
// byte, fewer fine-grain read<->write turnarounds.
//
// Ordering: x loads are independent of the matrix power but the dynamic
// while loop blocks hoisting — load FIRST, power while loads fly, FMA+store.

typedef float f4 __attribute__((ext_vector_type(4)));

__global__ __launch_bounds__(256)
void lin2d_apply(const float* __restrict__ x,
                 const float* __restrict__ linMt,
                 const int* __restrict__ Nptr,
                 float* __restrict__ out,
                 long long n4, long long ntail_pairs)
{
    const f4* __restrict__ xin = (const f4*)x;
    f4* __restrict__ o = (f4*)out;

    // 4 f4 per thread, block-strided: base + {0,256,512,768} -> every wave
    // access is a fully coalesced 16 B/lane burst.
    long long base = (long long)blockIdx.x * 1024 + threadIdx.x;
    long long i0 = base, i1 = base + 256, i2 = base + 512, i3 = base + 768;
    bool h0 = i0 < n4, h1 = i1 < n4, h2 = i2 < n4, h3 = i3 < n4;

    f4 v0 = {0,0,0,0}, v1 = {0,0,0,0}, v2 = {0,0,0,0}, v3 = {0,0,0,0};
    if (h0) v0 = xin[i0];
    if (h1) v1 = xin[i1];
    if (h2) v2 = xin[i2];
    if (h3) v3 = xin[i3];

    // A = linMt row-major 2x2.  y = x @ A  =>  y_j = x0*A[0][j] + x1*A[1][j].
    // M = A^N via binary exponentiation (~100 FMAs, overlapped with the
    // in-flight vector loads above).
    float b00 = linMt[0], b01 = linMt[1];
    float b10 = linMt[2], b11 = linMt[3];
    unsigned e = (unsigned)Nptr[0];
    float r00 = 1.f, r01 = 0.f, r10 = 0.f, r11 = 1.f;
    while (e) {
        if (e & 1u) {
            float t00 = r00*b00 + r01*b10;
            float t01 = r00*b01 + r01*b11;
            float t10 = r10*b00 + r11*b10;
            float t11 = r10*b01 + r11*b11;
            r00 = t00; r01 = t01; r10 = t10; r11 = t11;
        }
        e >>= 1;
        if (e) {
            float t00 = b00*b00 + b01*b10;
            float t01 = b00*b01 + b01*b11;
            float t10 = b10*b00 + b11*b10;
            float t11 = b10*b01 + b11*b11;
            b00 = t00; b01 = t01; b10 = t10; b11 = t11;
        }
    }

    #define APPLY(v) { f4 w;                      \
        w.x = (v).x * r00 + (v).y * r10;          \
        w.y = (v).x * r01 + (v).y * r11;          \
        w.z = (v).z * r00 + (v).w * r10;          \
        w.w = (v).z * r01 + (v).w * r11;          \
        (v) = w; }

    if (h0) { APPLY(v0); o[i0] = v0; }
    if (h1) { APPLY(v1); o[i1] = v1; }
    if (h2) { APPLY(v2); o[i2] = v2; }
    if (h3) { APPLY(v3); o[i3] = v3; }
    #undef APPLY

    // Tail (total floats not divisible by 4) — scalar, one thread.
    if (blockIdx.x == 0 && threadIdx.x == 0) {
        for (long long p = 0; p < ntail_pairs; ++p) {
            long long b = n4 * 4 + p * 2;
            float x0 = x[b], x1 = x[b + 1];
            out[b]     = x0 * r00 + x1 * r10;
            out[b + 1] = x0 * r01 + x1 * r11;
        }
    }
}

extern "C" void kernel_launch(void* const* d_in, const int* in_sizes, int n_in,
                              void* d_out, int out_size, void* d_ws, size_t ws_size,
                              hipStream_t stream) {
    const float* x     = (const float*)d_in[0];   // (B, 2) fp32, flat
    const float* linMt = (const float*)d_in[1];   // 2x2 fp32
    const int*   N     = (const int*)d_in[2];     // scalar int as 1-elem array
    float* out = (float*)d_out;

    long long total = (long long)in_sizes[0];     // B*2 floats
    long long n4 = total / 4;                     // float4 chunks
    long long ntail_pairs = (total - n4 * 4) / 2;

    // Exact-size launch: 4 f4 per thread -> n4/1024 blocks of 256.
    int blocks = (int)((n4 + 1023) / 1024);
    if (blocks < 1) blocks = 1;
    lin2d_apply<<<blocks, 256, 0, stream>>>(x, linMt, N, out, n4, ntail_pairs);
}